// Round 3
// baseline (655.545 us; speedup 1.0000x reference)
//
#include <hip/hip_runtime.h>

typedef __bf16 bf16;
typedef __bf16 bf16x8 __attribute__((ext_vector_type(8)));
typedef float f32x4 __attribute__((ext_vector_type(4)));

#define B_ 2
#define S_ 2048
#define D_ 2048
#define H_ 16
#define HKV_ 4
#define HD_ 128
#define QKVW 3072
#define QKW 2560                    // q+k columns (V handled separately)
#define SCALE 0.08838834764831845f  // 1/sqrt(128)
#define NEGINF -30000.0f            // finite -inf: exp underflows to 0, no inf-inf

// async global->LDS DMA, 16B per lane; LDS dest = wave-uniform base + lane*16
__device__ inline void gload16(const void* g, void* l) {
  __builtin_amdgcn_global_load_lds((const __attribute__((address_space(1))) unsigned int*)g,
                                   (__attribute__((address_space(3))) unsigned int*)l, 16, 0, 0);
}

__device__ inline unsigned short bfb(float v) {
  union { bf16 h; unsigned short u; } c;
  c.h = (bf16)v;
  return c.u;
}

// ---------------- dtype detection: bf16 or fp32 inputs? ----------------
__global__ void detect_dtype(const unsigned* __restrict__ xw, int* __restrict__ flag) {
  __shared__ int cnt;
  if (threadIdx.x == 0) cnt = 0;
  __syncthreads();
  unsigned w = xw[(size_t)threadIdx.x * 16384];
  unsigned low = w & 0xFFFFu;
  int e = (int)((low >> 7) & 0xFF);
  int vote = (low == 0u || (e >= 100 && e <= 140)) ? 1 : 0;
  atomicAdd(&cnt, vote);
  __syncthreads();
  if (threadIdx.x == 0) *flag = (cnt >= 128) ? 1 : 0;  // 1 = bf16, 0 = fp32
}

// ---------------- fused Wq/Wk/Wv transpose -> wqkvT (B^T layout) ----------------
__global__ __launch_bounds__(256) void transpose_qkvw(
    const void* __restrict__ Wq, const void* __restrict__ Wk, const void* __restrict__ Wv,
    bf16* __restrict__ wqkvT, const int* __restrict__ flag) {
  int z = blockIdx.z;
  const void* in = (z == 0) ? Wq : (z == 1) ? Wk : Wv;
  int cols = (z == 0) ? 2048 : 512;
  bf16* out = wqkvT + ((z == 0) ? 0 : (z == 1) ? 2048 * 2048 : 2560 * 2048);
  if (blockIdx.x * 32 >= cols) return;
  int fm = *flag;
  __shared__ float tile[32][33];
  int c0 = blockIdx.x * 32, r0 = blockIdx.y * 32;
  int tx = threadIdx.x, ty = threadIdx.y;  // 32 x 8
#pragma unroll
  for (int i = 0; i < 32; i += 8) {
    long idx = (long)(r0 + ty + i) * cols + c0 + tx;
    tile[ty + i][tx] = fm ? (float)((const bf16*)in)[idx] : ((const float*)in)[idx];
  }
  __syncthreads();
#pragma unroll
  for (int i = 0; i < 32; i += 8)
    out[(long)(c0 + ty + i) * 2048 + r0 + tx] = (bf16)tile[tx][ty + i];
}

// ---------------- generic transpose (+dtype-adaptive read) for Wo ----------------
__global__ __launch_bounds__(256) void transpose_cvt(
    const void* __restrict__ in, bf16* __restrict__ out,
    long in_stride, long out_stride, const int* __restrict__ flag) {
  __shared__ float tile[32][33];
  int fm = *flag;
  int c0 = blockIdx.x * 32, r0 = blockIdx.y * 32;
  int tx = threadIdx.x, ty = threadIdx.y;
#pragma unroll
  for (int i = 0; i < 32; i += 8) {
    long idx = (long)(r0 + ty + i) * in_stride + c0 + tx;
    tile[ty + i][tx] = fm ? (float)((const bf16*)in)[idx] : ((const float*)in)[idx];
  }
  __syncthreads();
#pragma unroll
  for (int i = 0; i < 32; i += 8)
    out[(long)(c0 + ty + i) * out_stride + r0 + tx] = (bf16)tile[tx][ty + i];
}

// ---------------- GEMM: C = A * Bt^T (m97-style global_load_lds staging) ----------------
#define BM 128
#define BN 128
#define BK 32

__global__ __launch_bounds__(256) void gemm_bt(
    const void* __restrict__ A, const bf16* __restrict__ Bt, void* __restrict__ C,
    int M, int N, int K, int ldc, int ncmax,
    bf16* __restrict__ vt_out, int vcol0,
    const int* __restrict__ flag, int adyn, int cdyn) {
  alignas(16) __shared__ bf16 la[BM * BK];  // unpadded: DMA lane-linear layout
  alignas(16) __shared__ bf16 lb[BN * BK];
  int fm = flag ? *flag : 1;
  bool af32 = adyn && !fm;
  bool cf32 = cdyn && !fm;
  int tid = threadIdx.x;
  int wave = tid >> 6, lane = tid & 63;
  int wr = wave >> 1, wc = wave & 1;
  int quad = lane >> 4, l16 = lane & 15;
  int m0 = blockIdx.y * BM, n0 = blockIdx.x * BN;

  f32x4 acc[4][4] = {};

  // DMA coords: lane covers row (wave*16 + lane/4), 8-elem chunk (lane%4)
  int sr = (wave << 4) + (lane >> 2);
  int sc = (lane & 3) << 3;
  const bf16* gb0 = Bt + (long)(n0 + sr) * K + sc;
  const bf16* gb1 = Bt + (long)(n0 + 64 + sr) * K + sc;
  bf16* lb0 = lb + (wave << 9);
  bf16* lb1 = lb + 2048 + (wave << 9);
  bf16* la0 = la + (wave << 9);
  bf16* la1 = la + 2048 + (wave << 9);
  const bf16* ga0 = nullptr; const bf16* ga1 = nullptr;
  const float* gaf = nullptr;
  int fr = tid >> 1, fh = (tid & 1) << 4;  // fp32-A path: row, 16-elem half
  if (af32) gaf = (const float*)A + (long)(m0 + fr) * K + fh;
  else { ga0 = (const bf16*)A + (long)(m0 + sr) * K + sc;
         ga1 = (const bf16*)A + (long)(m0 + 64 + sr) * K + sc; }
  bf16* law = la + fr * BK + fh;

  for (int k0 = 0; k0 < K; k0 += BK) {
    __syncthreads();  // all readers of previous tile done
    gload16(gb0 + k0, lb0);
    gload16(gb1 + k0, lb1);
    if (af32) {
      const float* fp = gaf + k0;
      alignas(16) bf16 t[16];
#pragma unroll
      for (int u = 0; u < 16; u += 4) {
        float4 f = *(const float4*)(fp + u);
        t[u] = (bf16)f.x; t[u + 1] = (bf16)f.y; t[u + 2] = (bf16)f.z; t[u + 3] = (bf16)f.w;
      }
      *(uint4*)law = *(uint4*)t;
      *(uint4*)(law + 8) = *(uint4*)(t + 8);
    } else {
      gload16(ga0 + k0, la0);
      gload16(ga1 + k0, la1);
    }
    __syncthreads();  // vmcnt+lgkm drained by compiler before barrier -> tile visible

    const bf16* pa = la + ((wr << 6) + l16) * BK + (quad << 3);
    const bf16* pb = lb + ((wc << 6) + l16) * BK + (quad << 3);
    bf16x8 af[4], bfr[4];
#pragma unroll
    for (int i = 0; i < 4; i++) af[i] = *(const bf16x8*)(pa + (i << 4) * BK);
#pragma unroll
    for (int j = 0; j < 4; j++) bfr[j] = *(const bf16x8*)(pb + (j << 4) * BK);
#pragma unroll
    for (int i = 0; i < 4; i++)
#pragma unroll
      for (int j = 0; j < 4; j++)
        acc[i][j] = __builtin_amdgcn_mfma_f32_16x16x32_bf16(af[i], bfr[j], acc[i][j], 0, 0, 0);
  }

  // C/D layout: col = lane&15, row = quad*4 + reg
  if (vt_out && n0 >= vcol0) {
    // V region of gemm1: write V^T[b][hd][s] directly (packed 8B stores)
#pragma unroll
    for (int i = 0; i < 4; i++)
#pragma unroll
      for (int j = 0; j < 4; j++) {
        int col = n0 + (wc << 6) + (j << 4) + l16;
        int hdg = col - vcol0;                            // 0..511 = kh*128+hd
        int row0 = m0 + (wr << 6) + (i << 4) + (quad << 2);
        int bb = row0 >> 11, s = row0 & 2047;             // row0 % 4 == 0: no b crossing
        ushort4 p;
        p.x = bfb(acc[i][j][0]); p.y = bfb(acc[i][j][1]);
        p.z = bfb(acc[i][j][2]); p.w = bfb(acc[i][j][3]);
        *(ushort4*)(vt_out + (((long)(bb * 512 + hdg)) << 11) + s) = p;
      }
  } else {
#pragma unroll
    for (int i = 0; i < 4; i++)
#pragma unroll
      for (int j = 0; j < 4; j++) {
        int col = n0 + (wc << 6) + (j << 4) + l16;
        if (col >= ncmax) continue;
#pragma unroll
        for (int r = 0; r < 4; r++) {
          long row = m0 + (wr << 6) + (i << 4) + (quad << 2) + r;
          float v = acc[i][j][r];
          if (cf32) ((float*)C)[row * ldc + col] = v;
          else      ((bf16*)C)[row * ldc + col] = (bf16)v;
        }
      }
  }
}

// ---------------- RoPE + scatter (Q pre-scaled by 1/sqrt(d)) ----------------
__global__ __launch_bounds__(256) void rope_scatter(
    const bf16* __restrict__ qkv, bf16* __restrict__ Q, bf16* __restrict__ Ko) {
  int row = blockIdx.x;  // b*S + s
  int b = row >> 11, s = row & 2047;
  int tid = threadIdx.x;
  const bf16* src = qkv + (long)row * QKW;
#pragma unroll
  for (int it = 0; it < 4; ++it) {
    int p = tid + it * 256;
    int h = p >> 6, i = p & 63;
    float x1 = (float)src[h * 128 + 2 * i];
    float x2 = (float)src[h * 128 + 2 * i + 1];
    float theta = __expf(-0.14391156831212787f * (float)i);  // 10000^(-2i/128)
    float sn, cs;
    sincosf((float)s * theta, &sn, &cs);
    long qb = ((long)(b * H_ + h) * S_ + s) * HD_;
    Q[qb + i]      = (bf16)((x1 * cs - x2 * sn) * SCALE);
    Q[qb + 64 + i] = (bf16)((x1 * sn + x2 * cs) * SCALE);
  }
  {
    int kh = tid >> 6, i = tid & 63;
    float x1 = (float)src[2048 + kh * 128 + 2 * i];
    float x2 = (float)src[2048 + kh * 128 + 2 * i + 1];
    float theta = __expf(-0.14391156831212787f * (float)i);
    float sn, cs;
    sincosf((float)s * theta, &sn, &cs);
    long kb = ((long)(b * HKV_ + kh) * S_ + s) * HD_;
    Ko[kb + i]      = (bf16)(x1 * cs - x2 * sn);
    Ko[kb + 64 + i] = (bf16)(x1 * sn + x2 * cs);
  }
}

// ---------------- flash attention: Q-frags in regs, reg-prefetched K/V ----------------
#define QSTR 136  // 128-wide rows: 272B stride -> rows spread 4 banks apart (uniform)
#define VSTR 72
#define PSTR 72

__global__ __launch_bounds__(256) void attn_kernel(
    const bf16* __restrict__ Q, const bf16* __restrict__ K,
    const bf16* __restrict__ Vt, bf16* __restrict__ O) {
  alignas(16) __shared__ bf16 Ks[64 * QSTR];   // 17.4 KB
  alignas(16) __shared__ bf16 Vs[128 * VSTR];  // 18.4 KB
  alignas(16) __shared__ bf16 Ps[64 * PSTR];   // 9.2 KB (wave-private rows)
  int qt = (int)gridDim.x - 1 - (int)blockIdx.x;  // longest blocks dispatch first
  int h = blockIdx.y, b = blockIdx.z;
  int kh = h >> 2;
  int tid = threadIdx.x, wave = tid >> 6, lane = tid & 63;
  int quad = lane >> 4, l16 = lane & 15;
  int q0 = qt * 64;
  const bf16* Qg = Q + ((long)(b * H_ + h) * S_ + q0) * HD_;
  const bf16* Kg = K + ((long)(b * HKV_ + kh) * S_) * HD_;
  const bf16* Vg = Vt + ((long)(b * HKV_ + kh) * HD_) * S_;

  // Q A-fragments in registers (pre-scaled in rope)
  bf16x8 qa[4];
  {
    const bf16* qrow = Qg + (wave * 16 + l16) * HD_ + quad * 8;
#pragma unroll
    for (int kk = 0; kk < 4; kk++) qa[kk] = *(const bf16x8*)(qrow + kk * 32);
  }

  // staging assignment + tile-0 preload into regs
  int krow = tid >> 2, kcol = (tid & 3) * 32;  // K tile: 64 x 128
  int vrow = tid >> 1, vcol = (tid & 1) * 32;  // V^T tile: 128 x 64
  const uint4* kg = (const uint4*)(Kg + (long)krow * HD_ + kcol);
  const uint4* vg = (const uint4*)(Vg + (long)vrow * S_ + vcol);
  uint4* kw = (uint4*)(Ks + krow * QSTR + kcol);
  uint4* vw = (uint4*)(Vs + vrow * VSTR + vcol);
  uint4 kr[4], vr[4];
#pragma unroll
  for (int u = 0; u < 4; u++) { kr[u] = kg[u]; vr[u] = vg[u]; }

  f32x4 Of[8] = {};
  float m_run[4], l_run[4];
#pragma unroll
  for (int r = 0; r < 4; r++) { m_run[r] = NEGINF; l_run[r] = 0.f; }

  for (int kt = 0; kt <= qt; ++kt) {
    __syncthreads();  // prev-tile readers done
#pragma unroll
    for (int u = 0; u < 4; u++) { kw[u] = kr[u]; vw[u] = vr[u]; }
    __syncthreads();  // tile visible
    if (kt < qt) {    // prefetch next tile; latency overlaps whole compute phase
      kg += 1024; vg += 8;
#pragma unroll
      for (int u = 0; u < 4; u++) { kr[u] = kg[u]; vr[u] = vg[u]; }
    }

    // S = Q K^T (16 q-rows x 64 keys per wave)
    f32x4 sf[4];
#pragma unroll
    for (int j = 0; j < 4; j++) {
      f32x4 a = {};
#pragma unroll
      for (int kk = 0; kk < 4; kk++) {
        bf16x8 kb = *(const bf16x8*)(Ks + (j * 16 + l16) * QSTR + kk * 32 + quad * 8);
        a = __builtin_amdgcn_mfma_f32_16x16x32_bf16(qa[kk], kb, a, 0, 0, 0);
      }
      sf[j] = a;
    }

    // online softmax (row = wave*16 + quad*4 + r, owned by the 16 lanes of this quad)
#pragma unroll
    for (int r = 0; r < 4; r++) {
      float sv[4];
      float mx = NEGINF;
      if (kt == qt) {  // diagonal tile: causal mask
        int rrow = wave * 16 + quad * 4 + r;
#pragma unroll
        for (int j = 0; j < 4; j++) {
          float v = sf[j][r];
          if (j * 16 + l16 > rrow) v = NEGINF;
          sv[j] = v; mx = fmaxf(mx, v);
        }
      } else {
#pragma unroll
        for (int j = 0; j < 4; j++) { sv[j] = sf[j][r]; mx = fmaxf(mx, sv[j]); }
      }
#pragma unroll
      for (int off = 1; off < 16; off <<= 1) mx = fmaxf(mx, __shfl_xor(mx, off));
      float mnew = fmaxf(m_run[r], mx);
      float alpha = __expf(m_run[r] - mnew);
      float rs = 0.f;
#pragma unroll
      for (int j = 0; j < 4; j++) {
        float p = __expf(sv[j] - mnew);
        rs += p;
        Ps[(wave * 16 + quad * 4 + r) * PSTR + j * 16 + l16] = (bf16)p;
      }
#pragma unroll
      for (int off = 1; off < 16; off <<= 1) rs += __shfl_xor(rs, off);
      l_run[r] = l_run[r] * alpha + rs;
      m_run[r] = mnew;
#pragma unroll
      for (int n = 0; n < 8; n++) Of[n][r] *= alpha;
    }
    // no barrier: Ps rows are wave-private; in-wave DS ordering suffices

    // O += P V
    const bf16* pp = Ps + (wave * 16 + l16) * PSTR + quad * 8;
#pragma unroll
    for (int kk = 0; kk < 2; kk++) {
      bf16x8 pa = *(const bf16x8*)(pp + kk * 32);
#pragma unroll
      for (int n = 0; n < 8; n++) {
        bf16x8 vb = *(const bf16x8*)(Vs + (n * 16 + l16) * VSTR + kk * 32 + quad * 8);
        Of[n] = __builtin_amdgcn_mfma_f32_16x16x32_bf16(pa, vb, Of[n], 0, 0, 0);
      }
    }
  }

  // epilogue: O /= l -> attno[b, s, h*128 + hd]
#pragma unroll
  for (int r = 0; r < 4; r++) {
    int grow = q0 + wave * 16 + quad * 4 + r;
    float inv = 1.0f / fmaxf(l_run[r], 1e-30f);
#pragma unroll
    for (int n = 0; n < 8; n++)
      O[((long)(b * S_) + grow) * D_ + h * HD_ + n * 16 + l16] = (bf16)(Of[n][r] * inv);
  }
}

// ---------------- launch ----------------
extern "C" void kernel_launch(void* const* d_in, const int* in_sizes, int n_in,
                              void* d_out, int out_size, void* d_ws, size_t ws_size,
                              hipStream_t stream) {
  const void* x  = d_in[0];
  const void* Wq = d_in[1];
  const void* Wk = d_in[2];
  const void* Wv = d_in[3];
  const void* Wo = d_in[4];
  bf16* ws = (bf16*)d_ws;
  int* flag = (int*)d_ws;

  // workspace (bf16 elem offsets), peak 23,068,688 elems = 46.1 MB
  bf16* qkv   = ws + 16;        // 4096 x 2560          gemm1 -> rope
  bf16* Vtb   = ws + 10485776;  // 2 x 512 x 2048       gemm1 epilogue -> attn
  bf16* Qb    = ws + 12582928;  // 2x16x2048x128        rope -> attn
  bf16* wqkvT = ws + 12582928;  // 3072x2048 (overlaps Qb; dead before rope writes)
  bf16* Kb    = ws + 20971536;  // 2x4x2048x128         rope -> attn
  bf16* attno = ws + 16;        // reuse qkv            attn -> gemm2
  bf16* woT   = ws + 10485776;  // reuse Vtb/Qb region  (transposed after attn)

  dim3 tb(32, 8);
  detect_dtype<<<1, 256, 0, stream>>>((const unsigned*)x, flag);
  transpose_qkvw<<<dim3(64, 64, 3), tb, 0, stream>>>(Wq, Wk, Wv, wqkvT, flag);
  // qkv = x @ [Wq|Wk|Wv]; q,k cols -> qkv (ldc 2560), v cols -> Vtb transposed
  gemm_bt<<<dim3(QKVW / BN, (B_ * S_) / BM), 256, 0, stream>>>(
      x, wqkvT, qkv, B_ * S_, QKVW, D_, QKW, QKW, Vtb, QKW, flag, 1, 0);
  rope_scatter<<<B_ * S_, 256, 0, stream>>>(qkv, Qb, Kb);
  attn_kernel<<<dim3(S_ / 64, H_, B_), 256, 0, stream>>>(Qb, Kb, Vtb, attno);
  transpose_cvt<<<dim3(64, 64, 1), tb, 0, stream>>>(Wo, woT, 2048, 2048, flag);
  // out = attno @ Wo (output dtype per flag)
  gemm_bt<<<dim3(D_ / BN, (B_ * S_) / BM), 256, 0, stream>>>(
      attno, woT, d_out, B_ * S_, D_, D_, D_, D_, nullptr, 0, flag, 0, 1);
}

// Round 4
// 624.645 us; speedup vs baseline: 1.0495x; 1.0495x over previous
//
#include <hip/hip_runtime.h>

typedef __bf16 bf16;
typedef __bf16 bf16x8 __attribute__((ext_vector_type(8)));
typedef float f32x4 __attribute__((ext_vector_type(4)));

#define B_ 2
#define S_ 2048
#define D_ 2048
#define H_ 16
#define HKV_ 4
#define HD_ 128
#define QKVW 3072
#define QKW 2560                    // q+k columns (V handled separately)
#define SCALE 0.08838834764831845f  // 1/sqrt(128)
#define NEGINF -30000.0f            // finite -inf: exp underflows to 0, no inf-inf

// async global->LDS DMA, 16B per lane; LDS dest = wave-uniform base + lane*16
__device__ inline void gload16(const void* g, void* l) {
  __builtin_amdgcn_global_load_lds((const __attribute__((address_space(1))) unsigned int*)g,
                                   (__attribute__((address_space(3))) unsigned int*)l, 16, 0, 0);
}

__device__ inline unsigned short bfb(float v) {
  union { bf16 h; unsigned short u; } c;
  c.h = (bf16)v;
  return c.u;
}

// ---------------- dtype detection: bf16 or fp32 inputs? ----------------
__global__ void detect_dtype(const unsigned* __restrict__ xw, int* __restrict__ flag) {
  __shared__ int cnt;
  if (threadIdx.x == 0) cnt = 0;
  __syncthreads();
  unsigned w = xw[(size_t)threadIdx.x * 16384];
  unsigned low = w & 0xFFFFu;
  int e = (int)((low >> 7) & 0xFF);
  int vote = (low == 0u || (e >= 100 && e <= 140)) ? 1 : 0;
  atomicAdd(&cnt, vote);
  __syncthreads();
  if (threadIdx.x == 0) *flag = (cnt >= 128) ? 1 : 0;  // 1 = bf16, 0 = fp32
}

// ---------------- fused Wq/Wk/Wv transpose -> wqkvT (B^T layout) ----------------
__global__ __launch_bounds__(256) void transpose_qkvw(
    const void* __restrict__ Wq, const void* __restrict__ Wk, const void* __restrict__ Wv,
    bf16* __restrict__ wqkvT, const int* __restrict__ flag) {
  int z = blockIdx.z;
  const void* in = (z == 0) ? Wq : (z == 1) ? Wk : Wv;
  int cols = (z == 0) ? 2048 : 512;
  bf16* out = wqkvT + ((z == 0) ? 0 : (z == 1) ? 2048 * 2048 : 2560 * 2048);
  if (blockIdx.x * 32 >= cols) return;
  int fm = *flag;
  __shared__ float tile[32][33];
  int c0 = blockIdx.x * 32, r0 = blockIdx.y * 32;
  int tx = threadIdx.x, ty = threadIdx.y;  // 32 x 8
#pragma unroll
  for (int i = 0; i < 32; i += 8) {
    long idx = (long)(r0 + ty + i) * cols + c0 + tx;
    tile[ty + i][tx] = fm ? (float)((const bf16*)in)[idx] : ((const float*)in)[idx];
  }
  __syncthreads();
#pragma unroll
  for (int i = 0; i < 32; i += 8)
    out[(long)(c0 + ty + i) * 2048 + r0 + tx] = (bf16)tile[tx][ty + i];
}

// ---------------- generic transpose (+dtype-adaptive read) for Wo ----------------
__global__ __launch_bounds__(256) void transpose_cvt(
    const void* __restrict__ in, bf16* __restrict__ out,
    long in_stride, long out_stride, const int* __restrict__ flag) {
  __shared__ float tile[32][33];
  int fm = *flag;
  int c0 = blockIdx.x * 32, r0 = blockIdx.y * 32;
  int tx = threadIdx.x, ty = threadIdx.y;
#pragma unroll
  for (int i = 0; i < 32; i += 8) {
    long idx = (long)(r0 + ty + i) * in_stride + c0 + tx;
    tile[ty + i][tx] = fm ? (float)((const bf16*)in)[idx] : ((const float*)in)[idx];
  }
  __syncthreads();
#pragma unroll
  for (int i = 0; i < 32; i += 8)
    out[(long)(c0 + ty + i) * out_stride + r0 + tx] = (bf16)tile[tx][ty + i];
}

// ---------------- GEMM: C = A * Bt^T (m97-style global_load_lds staging) ----------------
#define BM 128
#define BN 128
#define BK 32

__global__ __launch_bounds__(256) void gemm_bt(
    const void* __restrict__ A, const bf16* __restrict__ Bt, void* __restrict__ C,
    int M, int N, int K, int ldc, int ncmax,
    bf16* __restrict__ vt_out, int vcol0,
    const int* __restrict__ flag, int adyn, int cdyn) {
  alignas(16) __shared__ bf16 la[BM * BK];  // unpadded: DMA lane-linear layout
  alignas(16) __shared__ bf16 lb[BN * BK];
  int fm = flag ? *flag : 1;
  bool af32 = adyn && !fm;
  bool cf32 = cdyn && !fm;
  int tid = threadIdx.x;
  int wave = tid >> 6, lane = tid & 63;
  int wr = wave >> 1, wc = wave & 1;
  int quad = lane >> 4, l16 = lane & 15;
  int m0 = blockIdx.y * BM, n0 = blockIdx.x * BN;

  f32x4 acc[4][4] = {};

  // DMA coords: lane covers row (wave*16 + lane/4), 8-elem chunk (lane%4)
  int sr = (wave << 4) + (lane >> 2);
  int sc = (lane & 3) << 3;
  const bf16* gb0 = Bt + (long)(n0 + sr) * K + sc;
  const bf16* gb1 = Bt + (long)(n0 + 64 + sr) * K + sc;
  bf16* lb0 = lb + (wave << 9);
  bf16* lb1 = lb + 2048 + (wave << 9);
  bf16* la0 = la + (wave << 9);
  bf16* la1 = la + 2048 + (wave << 9);
  const bf16* ga0 = nullptr; const bf16* ga1 = nullptr;
  const float* gaf = nullptr;
  int fr = tid >> 1, fh = (tid & 1) << 4;  // fp32-A path: row, 16-elem half
  if (af32) gaf = (const float*)A + (long)(m0 + fr) * K + fh;
  else { ga0 = (const bf16*)A + (long)(m0 + sr) * K + sc;
         ga1 = (const bf16*)A + (long)(m0 + 64 + sr) * K + sc; }
  bf16* law = la + fr * BK + fh;

  for (int k0 = 0; k0 < K; k0 += BK) {
    __syncthreads();  // all readers of previous tile done
    gload16(gb0 + k0, lb0);
    gload16(gb1 + k0, lb1);
    if (af32) {
      const float* fp = gaf + k0;
      alignas(16) bf16 t[16];
#pragma unroll
      for (int u = 0; u < 16; u += 4) {
        float4 f = *(const float4*)(fp + u);
        t[u] = (bf16)f.x; t[u + 1] = (bf16)f.y; t[u + 2] = (bf16)f.z; t[u + 3] = (bf16)f.w;
      }
      *(uint4*)law = *(uint4*)t;
      *(uint4*)(law + 8) = *(uint4*)(t + 8);
    } else {
      gload16(ga0 + k0, la0);
      gload16(ga1 + k0, la1);
    }
    __syncthreads();  // vmcnt+lgkm drained by compiler before barrier -> tile visible

    const bf16* pa = la + ((wr << 6) + l16) * BK + (quad << 3);
    const bf16* pb = lb + ((wc << 6) + l16) * BK + (quad << 3);
    bf16x8 af[4], bfr[4];
#pragma unroll
    for (int i = 0; i < 4; i++) af[i] = *(const bf16x8*)(pa + (i << 4) * BK);
#pragma unroll
    for (int j = 0; j < 4; j++) bfr[j] = *(const bf16x8*)(pb + (j << 4) * BK);
#pragma unroll
    for (int i = 0; i < 4; i++)
#pragma unroll
      for (int j = 0; j < 4; j++)
        acc[i][j] = __builtin_amdgcn_mfma_f32_16x16x32_bf16(af[i], bfr[j], acc[i][j], 0, 0, 0);
  }

  // C/D layout: col = lane&15, row = quad*4 + reg
  if (vt_out && n0 >= vcol0) {
    // V region of gemm1: write V^T[b][hd][s] directly (packed 8B stores)
#pragma unroll
    for (int i = 0; i < 4; i++)
#pragma unroll
      for (int j = 0; j < 4; j++) {
        int col = n0 + (wc << 6) + (j << 4) + l16;
        int hdg = col - vcol0;                            // 0..511 = kh*128+hd
        int row0 = m0 + (wr << 6) + (i << 4) + (quad << 2);
        int bb = row0 >> 11, s = row0 & 2047;             // row0 % 4 == 0: no b crossing
        ushort4 p;
        p.x = bfb(acc[i][j][0]); p.y = bfb(acc[i][j][1]);
        p.z = bfb(acc[i][j][2]); p.w = bfb(acc[i][j][3]);
        *(ushort4*)(vt_out + (((long)(bb * 512 + hdg)) << 11) + s) = p;
      }
  } else {
#pragma unroll
    for (int i = 0; i < 4; i++)
#pragma unroll
      for (int j = 0; j < 4; j++) {
        int col = n0 + (wc << 6) + (j << 4) + l16;
        if (col >= ncmax) continue;
#pragma unroll
        for (int r = 0; r < 4; r++) {
          long row = m0 + (wr << 6) + (i << 4) + (quad << 2) + r;
          float v = acc[i][j][r];
          if (cf32) ((float*)C)[row * ldc + col] = v;
          else      ((bf16*)C)[row * ldc + col] = (bf16)v;
        }
      }
  }
}

// ---------------- RoPE + scatter (Q pre-scaled by 1/sqrt(d)) ----------------
__global__ __launch_bounds__(256) void rope_scatter(
    const bf16* __restrict__ qkv, bf16* __restrict__ Q, bf16* __restrict__ Ko) {
  int row = blockIdx.x;  // b*S + s
  int b = row >> 11, s = row & 2047;
  int tid = threadIdx.x;
  const bf16* src = qkv + (long)row * QKW;
#pragma unroll
  for (int it = 0; it < 4; ++it) {
    int p = tid + it * 256;
    int h = p >> 6, i = p & 63;
    float x1 = (float)src[h * 128 + 2 * i];
    float x2 = (float)src[h * 128 + 2 * i + 1];
    float theta = __expf(-0.14391156831212787f * (float)i);  // 10000^(-2i/128)
    float sn, cs;
    sincosf((float)s * theta, &sn, &cs);
    long qb = ((long)(b * H_ + h) * S_ + s) * HD_;
    Q[qb + i]      = (bf16)((x1 * cs - x2 * sn) * SCALE);
    Q[qb + 64 + i] = (bf16)((x1 * sn + x2 * cs) * SCALE);
  }
  {
    int kh = tid >> 6, i = tid & 63;
    float x1 = (float)src[2048 + kh * 128 + 2 * i];
    float x2 = (float)src[2048 + kh * 128 + 2 * i + 1];
    float theta = __expf(-0.14391156831212787f * (float)i);
    float sn, cs;
    sincosf((float)s * theta, &sn, &cs);
    long kb = ((long)(b * HKV_ + kh) * S_ + s) * HD_;
    Ko[kb + i]      = (bf16)(x1 * cs - x2 * sn);
    Ko[kb + 64 + i] = (bf16)(x1 * sn + x2 * cs);
  }
}

// ---------------- flash attention: S^T = K Q^T orientation ----------------
// Row-state (m, l, alpha) lives per-lane (l16 = q-row): 2-shuffle max tree, 1 exp/row/iter,
// l reduced across quads only once at the end. Ps written as packed 8B (4 consecutive keys).
#define QSTR 136  // K tile rows (keys) x 128 hd
#define VSTR 72   // V^T rows (hd) x 64 keys
#define PSTR 72   // P rows (qrow) x 64 keys

__global__ __launch_bounds__(256, 2) void attn_kernel(
    const bf16* __restrict__ Q, const bf16* __restrict__ K,
    const bf16* __restrict__ Vt, bf16* __restrict__ O) {
  alignas(16) __shared__ bf16 Ks[64 * QSTR];   // 17.4 KB
  alignas(16) __shared__ bf16 Vs[128 * VSTR];  // 18.4 KB
  alignas(16) __shared__ bf16 Ps[64 * PSTR];   // 9.2 KB (wave-private rows)
  int qt = (int)gridDim.x - 1 - (int)blockIdx.x;  // longest blocks dispatch first
  int h = blockIdx.y, b = blockIdx.z;
  int kh = h >> 2;
  int tid = threadIdx.x, wave = tid >> 6, lane = tid & 63;
  int quad = lane >> 4, l16 = lane & 15;
  int q0 = qt * 64;
  const bf16* Qg = Q + ((long)(b * H_ + h) * S_ + q0) * HD_;
  const bf16* Kg = K + ((long)(b * HKV_ + kh) * S_) * HD_;
  const bf16* Vg = Vt + ((long)(b * HKV_ + kh) * HD_) * S_;

  // Q B-fragments in registers (pre-scaled by 1/sqrt(d) in rope); lane l16 = q-row
  bf16x8 qa[4];
  {
    const bf16* qrow = Qg + (wave * 16 + l16) * HD_ + quad * 8;
#pragma unroll
    for (int kk = 0; kk < 4; kk++) qa[kk] = *(const bf16x8*)(qrow + kk * 32);
  }

  // staging assignment + tile-0 preload into regs (32 VGPRs; launch_bounds caps at 256 -> no spill)
  int krow = tid >> 2, kcol = (tid & 3) * 32;  // K tile: 64 x 128
  int vrow = tid >> 1, vcol = (tid & 1) * 32;  // V^T tile: 128 x 64
  const uint4* kg = (const uint4*)(Kg + (long)krow * HD_ + kcol);
  const uint4* vg = (const uint4*)(Vg + (long)vrow * S_ + vcol);
  uint4* kw = (uint4*)(Ks + krow * QSTR + kcol);
  uint4* vw = (uint4*)(Vs + vrow * VSTR + vcol);
  uint4 kr[4], vr[4];
#pragma unroll
  for (int u = 0; u < 4; u++) { kr[u] = kg[u]; vr[u] = vg[u]; }

  f32x4 Of[8] = {};
  float m_run = NEGINF, l_run = 0.f;  // state for q-row (wave*16 + l16)

  for (int kt = 0; kt <= qt; ++kt) {
    __syncthreads();  // prev-tile readers done
#pragma unroll
    for (int u = 0; u < 4; u++) { kw[u] = kr[u]; vw[u] = vr[u]; }
    __syncthreads();  // tile visible
    if (kt < qt) {    // prefetch next tile; latency overlaps compute
      kg += 1024; vg += 8;
#pragma unroll
      for (int u = 0; u < 4; u++) { kr[u] = kg[u]; vr[u] = vg[u]; }
    }

    // S^T = K Q^T: A = K-frag (m=key), B = Q-frag (n=qrow)
    // D col(l16) = qrow, row(quad*4+r) = key within 16-block jb
    bool diag = (kt == qt);
    f32x4 sf[4];
#pragma unroll
    for (int jb = 0; jb < 4; jb++) {
      if (diag && jb > wave) {  // fully-masked key block: skip MFMA
        sf[jb] = (f32x4){NEGINF, NEGINF, NEGINF, NEGINF};
        continue;
      }
      f32x4 a = {};
#pragma unroll
      for (int kk = 0; kk < 4; kk++) {
        bf16x8 kf = *(const bf16x8*)(Ks + (jb * 16 + l16) * QSTR + kk * 32 + quad * 8);
        a = __builtin_amdgcn_mfma_f32_16x16x32_bf16(kf, qa[kk], a, 0, 0, 0);
      }
      sf[jb] = a;
    }
    if (diag) {  // partial mask on key block jb == wave: key quad*4+r > qrow l16
#pragma unroll
      for (int r = 0; r < 4; r++)
        if (quad * 4 + r > l16) sf[wave][r] = NEGINF;
    }

    // row max: local over 16 values + 2-shuffle cross-quad tree
    float mx = NEGINF;
#pragma unroll
    for (int jb = 0; jb < 4; jb++)
#pragma unroll
      for (int r = 0; r < 4; r++) mx = fmaxf(mx, sf[jb][r]);
    mx = fmaxf(mx, __shfl_xor(mx, 16));
    mx = fmaxf(mx, __shfl_xor(mx, 32));
    float mnew = fmaxf(m_run, mx);
    float alpha = __expf(m_run - mnew);
    m_run = mnew;

    // p = exp(s - m), per-lane partial l, packed Ps stores (4 consecutive keys)
    float ls = 0.f;
#pragma unroll
    for (int jb = 0; jb < 4; jb++) {
      float p0 = __expf(sf[jb][0] - mnew);
      float p1 = __expf(sf[jb][1] - mnew);
      float p2 = __expf(sf[jb][2] - mnew);
      float p3 = __expf(sf[jb][3] - mnew);
      ls += (p0 + p1) + (p2 + p3);
      ushort4 pk;
      pk.x = bfb(p0); pk.y = bfb(p1); pk.z = bfb(p2); pk.w = bfb(p3);
      *(ushort4*)(Ps + (wave * 16 + l16) * PSTR + jb * 16 + quad * 4) = pk;
    }
    l_run = l_run * alpha + ls;

    // rescale O: alpha for row quad*4+r held by lane (quad*4+r)
#pragma unroll
    for (int r = 0; r < 4; r++) {
      float ar = __shfl(alpha, quad * 4 + r);
#pragma unroll
      for (int n = 0; n < 8; n++) Of[n][r] *= ar;
    }
    // no barrier: Ps rows are wave-private; in-wave DS ordering suffices

    // O += P V
#pragma unroll
    for (int kk = 0; kk < 2; kk++) {
      bf16x8 pa = *(const bf16x8*)(Ps + (wave * 16 + l16) * PSTR + kk * 32 + quad * 8);
#pragma unroll
      for (int n = 0; n < 8; n++) {
        bf16x8 vb = *(const bf16x8*)(Vs + (n * 16 + l16) * VSTR + kk * 32 + quad * 8);
        Of[n] = __builtin_amdgcn_mfma_f32_16x16x32_bf16(pa, vb, Of[n], 0, 0, 0);
      }
    }
  }

  // epilogue: reduce l across quads (each lane holds partial for row l16)
  l_run += __shfl_xor(l_run, 16);
  l_run += __shfl_xor(l_run, 32);
  float inv = 1.0f / fmaxf(l_run, 1e-30f);
#pragma unroll
  for (int r = 0; r < 4; r++) {
    float ir = __shfl(inv, quad * 4 + r);
    int grow = q0 + wave * 16 + quad * 4 + r;
#pragma unroll
    for (int n = 0; n < 8; n++)
      O[((long)(b * S_) + grow) * D_ + h * HD_ + n * 16 + l16] = (bf16)(Of[n][r] * ir);
  }
}

// ---------------- launch ----------------
extern "C" void kernel_launch(void* const* d_in, const int* in_sizes, int n_in,
                              void* d_out, int out_size, void* d_ws, size_t ws_size,
                              hipStream_t stream) {
  const void* x  = d_in[0];
  const void* Wq = d_in[1];
  const void* Wk = d_in[2];
  const void* Wv = d_in[3];
  const void* Wo = d_in[4];
  bf16* ws = (bf16*)d_ws;
  int* flag = (int*)d_ws;

  // workspace (bf16 elem offsets), peak 23,068,688 elems = 46.1 MB
  bf16* qkv   = ws + 16;        // 4096 x 2560          gemm1 -> rope
  bf16* Vtb   = ws + 10485776;  // 2 x 512 x 2048       gemm1 epilogue -> attn
  bf16* Qb    = ws + 12582928;  // 2x16x2048x128        rope -> attn
  bf16* wqkvT = ws + 12582928;  // 3072x2048 (overlaps Qb; dead before rope writes)
  bf16* Kb    = ws + 20971536;  // 2x4x2048x128         rope -> attn
  bf16* attno = ws + 16;        // reuse qkv            attn -> gemm2
  bf16* woT   = ws + 10485776;  // reuse Vtb/Qb region  (transposed after attn)

  dim3 tb(32, 8);
  detect_dtype<<<1, 256, 0, stream>>>((const unsigned*)x, flag);
  transpose_qkvw<<<dim3(64, 64, 3), tb, 0, stream>>>(Wq, Wk, Wv, wqkvT, flag);
  // qkv = x @ [Wq|Wk|Wv]; q,k cols -> qkv (ldc 2560), v cols -> Vtb transposed
  gemm_bt<<<dim3(QKVW / BN, (B_ * S_) / BM), 256, 0, stream>>>(
      x, wqkvT, qkv, B_ * S_, QKVW, D_, QKW, QKW, Vtb, QKW, flag, 1, 0);
  rope_scatter<<<B_ * S_, 256, 0, stream>>>(qkv, Qb, Kb);
  attn_kernel<<<dim3(S_ / 64, H_, B_), 256, 0, stream>>>(Qb, Kb, Vtb, attno);
  transpose_cvt<<<dim3(64, 64, 1), tb, 0, stream>>>(Wo, woT, 2048, 2048, flag);
  // out = attno @ Wo (output dtype per flag)
  gemm_bt<<<dim3(D_ / BN, (B_ * S_) / BM), 256, 0, stream>>>(
      attno, woT, d_out, B_ * S_, D_, D_, D_, D_, nullptr, 0, flag, 0, 1);
}

// Round 5
// 614.819 us; speedup vs baseline: 1.0662x; 1.0160x over previous
//
#include <hip/hip_runtime.h>

typedef __bf16 bf16;
typedef __bf16 bf16x8 __attribute__((ext_vector_type(8)));
typedef float f32x4 __attribute__((ext_vector_type(4)));
typedef short s16x4 __attribute__((ext_vector_type(4)));

#define B_ 2
#define S_ 2048
#define D_ 2048
#define H_ 16
#define HKV_ 4
#define HD_ 128
#define QKVW 3072
#define QKW 2560                    // q+k columns (V handled separately)
#define SCALE 0.08838834764831845f  // 1/sqrt(128)
#define NEGINF -30000.0f            // finite -inf: exp underflows to 0, no inf-inf

// async global->LDS DMA, 16B per lane; LDS dest = wave-uniform base + lane*16
__device__ inline void gload16(const void* g, void* l) {
  __builtin_amdgcn_global_load_lds((const __attribute__((address_space(1))) unsigned int*)g,
                                   (__attribute__((address_space(3))) unsigned int*)l, 16, 0, 0);
}

__device__ inline unsigned short bfb(float v) {
  union { bf16 h; unsigned short u; } c;
  c.h = (bf16)v;
  return c.u;
}

// ---------------- dtype detection: bf16 or fp32 inputs? ----------------
__global__ void detect_dtype(const unsigned* __restrict__ xw, int* __restrict__ flag) {
  __shared__ int cnt;
  if (threadIdx.x == 0) cnt = 0;
  __syncthreads();
  unsigned w = xw[(size_t)threadIdx.x * 16384];
  unsigned low = w & 0xFFFFu;
  int e = (int)((low >> 7) & 0xFF);
  int vote = (low == 0u || (e >= 100 && e <= 140)) ? 1 : 0;
  atomicAdd(&cnt, vote);
  __syncthreads();
  if (threadIdx.x == 0) *flag = (cnt >= 128) ? 1 : 0;  // 1 = bf16, 0 = fp32
}

// ---------------- fused Wq/Wk/Wv transpose -> wqkvT (B^T layout) ----------------
__global__ __launch_bounds__(256) void transpose_qkvw(
    const void* __restrict__ Wq, const void* __restrict__ Wk, const void* __restrict__ Wv,
    bf16* __restrict__ wqkvT, const int* __restrict__ flag) {
  int z = blockIdx.z;
  const void* in = (z == 0) ? Wq : (z == 1) ? Wk : Wv;
  int cols = (z == 0) ? 2048 : 512;
  bf16* out = wqkvT + ((z == 0) ? 0 : (z == 1) ? 2048 * 2048 : 2560 * 2048);
  if (blockIdx.x * 32 >= cols) return;
  int fm = *flag;
  __shared__ float tile[32][33];
  int c0 = blockIdx.x * 32, r0 = blockIdx.y * 32;
  int tx = threadIdx.x, ty = threadIdx.y;  // 32 x 8
#pragma unroll
  for (int i = 0; i < 32; i += 8) {
    long idx = (long)(r0 + ty + i) * cols + c0 + tx;
    tile[ty + i][tx] = fm ? (float)((const bf16*)in)[idx] : ((const float*)in)[idx];
  }
  __syncthreads();
#pragma unroll
  for (int i = 0; i < 32; i += 8)
    out[(long)(c0 + ty + i) * 2048 + r0 + tx] = (bf16)tile[tx][ty + i];
}

// ---------------- generic transpose (+dtype-adaptive read) for Wo ----------------
__global__ __launch_bounds__(256) void transpose_cvt(
    const void* __restrict__ in, bf16* __restrict__ out,
    long in_stride, long out_stride, const int* __restrict__ flag) {
  __shared__ float tile[32][33];
  int fm = *flag;
  int c0 = blockIdx.x * 32, r0 = blockIdx.y * 32;
  int tx = threadIdx.x, ty = threadIdx.y;
#pragma unroll
  for (int i = 0; i < 32; i += 8) {
    long idx = (long)(r0 + ty + i) * in_stride + c0 + tx;
    tile[ty + i][tx] = fm ? (float)((const bf16*)in)[idx] : ((const float*)in)[idx];
  }
  __syncthreads();
#pragma unroll
  for (int i = 0; i < 32; i += 8)
    out[(long)(c0 + ty + i) * out_stride + r0 + tx] = (bf16)tile[tx][ty + i];
}

// ---------------- GEMM: C = A * Bt^T (m97-style global_load_lds staging) ----------------
#define BM 128
#define BN 128
#define BK 32

__global__ __launch_bounds__(256) void gemm_bt(
    const void* __restrict__ A, const bf16* __restrict__ Bt, void* __restrict__ C,
    int M, int N, int K, int ldc, int ncmax,
    bf16* __restrict__ vt_out, int vcol0,
    const int* __restrict__ flag, int adyn, int cdyn) {
  alignas(16) __shared__ bf16 la[BM * BK];  // unpadded: DMA lane-linear layout
  alignas(16) __shared__ bf16 lb[BN * BK];
  int fm = flag ? *flag : 1;
  bool af32 = adyn && !fm;
  bool cf32 = cdyn && !fm;
  int tid = threadIdx.x;
  int wave = tid >> 6, lane = tid & 63;
  int wr = wave >> 1, wc = wave & 1;
  int quad = lane >> 4, l16 = lane & 15;
  int m0 = blockIdx.y * BM, n0 = blockIdx.x * BN;

  f32x4 acc[4][4] = {};

  // DMA coords: lane covers row (wave*16 + lane/4), 8-elem chunk (lane%4)
  int sr = (wave << 4) + (lane >> 2);
  int sc = (lane & 3) << 3;
  const bf16* gb0 = Bt + (long)(n0 + sr) * K + sc;
  const bf16* gb1 = Bt + (long)(n0 + 64 + sr) * K + sc;
  bf16* lb0 = lb + (wave << 9);
  bf16* lb1 = lb + 2048 + (wave << 9);
  bf16* la0 = la + (wave << 9);
  bf16* la1 = la + 2048 + (wave << 9);
  const bf16* ga0 = nullptr; const bf16* ga1 = nullptr;
  const float* gaf = nullptr;
  int fr = tid >> 1, fh = (tid & 1) << 4;  // fp32-A path: row, 16-elem half
  if (af32) gaf = (const float*)A + (long)(m0 + fr) * K + fh;
  else { ga0 = (const bf16*)A + (long)(m0 + sr) * K + sc;
         ga1 = (const bf16*)A + (long)(m0 + 64 + sr) * K + sc; }
  bf16* law = la + fr * BK + fh;

  for (int k0 = 0; k0 < K; k0 += BK) {
    __syncthreads();  // all readers of previous tile done
    gload16(gb0 + k0, lb0);
    gload16(gb1 + k0, lb1);
    if (af32) {
      const float* fp = gaf + k0;
      alignas(16) bf16 t[16];
#pragma unroll
      for (int u = 0; u < 16; u += 4) {
        float4 f = *(const float4*)(fp + u);
        t[u] = (bf16)f.x; t[u + 1] = (bf16)f.y; t[u + 2] = (bf16)f.z; t[u + 3] = (bf16)f.w;
      }
      *(uint4*)law = *(uint4*)t;
      *(uint4*)(law + 8) = *(uint4*)(t + 8);
    } else {
      gload16(ga0 + k0, la0);
      gload16(ga1 + k0, la1);
    }
    __syncthreads();  // vmcnt+lgkm drained by compiler before barrier -> tile visible

    const bf16* pa = la + ((wr << 6) + l16) * BK + (quad << 3);
    const bf16* pb = lb + ((wc << 6) + l16) * BK + (quad << 3);
    bf16x8 af[4], bfr[4];
#pragma unroll
    for (int i = 0; i < 4; i++) af[i] = *(const bf16x8*)(pa + (i << 4) * BK);
#pragma unroll
    for (int j = 0; j < 4; j++) bfr[j] = *(const bf16x8*)(pb + (j << 4) * BK);
#pragma unroll
    for (int i = 0; i < 4; i++)
#pragma unroll
      for (int j = 0; j < 4; j++)
        acc[i][j] = __builtin_amdgcn_mfma_f32_16x16x32_bf16(af[i], bfr[j], acc[i][j], 0, 0, 0);
  }

  // C/D layout: col = lane&15, row = quad*4 + reg
  if (vt_out && n0 >= vcol0) {
    // V region of gemm1: write V^T[b][hd][s] directly (packed 8B stores)
#pragma unroll
    for (int i = 0; i < 4; i++)
#pragma unroll
      for (int j = 0; j < 4; j++) {
        int col = n0 + (wc << 6) + (j << 4) + l16;
        int hdg = col - vcol0;                            // 0..511 = kh*128+hd
        int row0 = m0 + (wr << 6) + (i << 4) + (quad << 2);
        int bb = row0 >> 11, s = row0 & 2047;             // row0 % 4 == 0: no b crossing
        ushort4 p;
        p.x = bfb(acc[i][j][0]); p.y = bfb(acc[i][j][1]);
        p.z = bfb(acc[i][j][2]); p.w = bfb(acc[i][j][3]);
        *(ushort4*)(vt_out + (((long)(bb * 512 + hdg)) << 11) + s) = p;
      }
  } else {
#pragma unroll
    for (int i = 0; i < 4; i++)
#pragma unroll
      for (int j = 0; j < 4; j++) {
        int col = n0 + (wc << 6) + (j << 4) + l16;
        if (col >= ncmax) continue;
#pragma unroll
        for (int r = 0; r < 4; r++) {
          long row = m0 + (wr << 6) + (i << 4) + (quad << 2) + r;
          float v = acc[i][j][r];
          if (cf32) ((float*)C)[row * ldc + col] = v;
          else      ((bf16*)C)[row * ldc + col] = (bf16)v;
        }
      }
  }
}

// ---------------- RoPE + scatter (Q pre-scaled by 1/sqrt(d)) ----------------
__global__ __launch_bounds__(256) void rope_scatter(
    const bf16* __restrict__ qkv, bf16* __restrict__ Q, bf16* __restrict__ Ko) {
  int row = blockIdx.x;  // b*S + s
  int b = row >> 11, s = row & 2047;
  int tid = threadIdx.x;
  const bf16* src = qkv + (long)row * QKW;
#pragma unroll
  for (int it = 0; it < 4; ++it) {
    int p = tid + it * 256;
    int h = p >> 6, i = p & 63;
    float x1 = (float)src[h * 128 + 2 * i];
    float x2 = (float)src[h * 128 + 2 * i + 1];
    float theta = __expf(-0.14391156831212787f * (float)i);  // 10000^(-2i/128)
    float sn, cs;
    sincosf((float)s * theta, &sn, &cs);
    long qb = ((long)(b * H_ + h) * S_ + s) * HD_;
    Q[qb + i]      = (bf16)((x1 * cs - x2 * sn) * SCALE);
    Q[qb + 64 + i] = (bf16)((x1 * sn + x2 * cs) * SCALE);
  }
  {
    int kh = tid >> 6, i = tid & 63;
    float x1 = (float)src[2048 + kh * 128 + 2 * i];
    float x2 = (float)src[2048 + kh * 128 + 2 * i + 1];
    float theta = __expf(-0.14391156831212787f * (float)i);
    float sn, cs;
    sincosf((float)s * theta, &sn, &cs);
    long kb = ((long)(b * HKV_ + kh) * S_ + s) * HD_;
    Ko[kb + i]      = (bf16)(x1 * cs - x2 * sn);
    Ko[kb + 64 + i] = (bf16)(x1 * sn + x2 * cs);
  }
}

// ---------------- flash attention ----------------
// S^T = K Q^T (C-layout: lane l16 = qrow, regs = 4 consecutive keys). The S accumulator
// registers are EXACTLY the B-operand layout of v_mfma_f32_16x16x16_bf16 (k = quad*4+j),
// so PV computes O^T += V^T_frag * P^T straight from registers: no P LDS round-trip,
// per-lane (qrow) softmax state, alpha applied without shuffles.
// K/V staged via LDS double-buffer; one barrier per iteration; NO dynamic indexing anywhere.
#define KSTR 136  // K tile row stride (272B, 16B-aligned)
#define VSTR 72   // V^T tile row stride (144B, 8B-aligned)
#define KTILE (64 * KSTR)
#define VTILE (128 * VSTR)

__global__ __launch_bounds__(256, 2) void attn_kernel(
    const bf16* __restrict__ Q, const bf16* __restrict__ K,
    const bf16* __restrict__ Vt, bf16* __restrict__ O) {
  alignas(16) __shared__ bf16 Ks[2 * KTILE];  // 34.8 KB
  alignas(16) __shared__ bf16 Vs[2 * VTILE];  // 36.9 KB  (total 70 KB -> 2 blocks/CU)
  int qt = (int)gridDim.x - 1 - (int)blockIdx.x;  // longest blocks dispatch first
  int h = blockIdx.y, b = blockIdx.z;
  int kh = h >> 2;
  int tid = threadIdx.x, wave = tid >> 6, lane = tid & 63;
  int quad = lane >> 4, l16 = lane & 15;
  int q0 = qt * 64;
  const bf16* Qg = Q + ((long)(b * H_ + h) * S_ + q0) * HD_;
  const bf16* Kg = K + ((long)(b * HKV_ + kh) * S_) * HD_;
  const bf16* Vg = Vt + ((long)(b * HKV_ + kh) * HD_) * S_;

  // Q B-fragments in registers (pre-scaled by 1/sqrt(d)); lane l16 = qrow
  bf16x8 qb[4];
  {
    const bf16* qrow = Qg + (wave * 16 + l16) * HD_ + quad * 8;
#pragma unroll
    for (int kk = 0; kk < 4; kk++) qb[kk] = *(const bf16x8*)(qrow + kk * 32);
  }

  // staging thread assignment
  int krow = tid >> 2, kcol = (tid & 3) * 32;  // K tile: 64 rows x 128 hd
  int vrow = tid >> 1, vcol = (tid & 1) * 32;  // V^T tile: 128 hd x 64 keys
  const uint4* kgp = (const uint4*)(Kg + (long)krow * HD_ + kcol);
  const uint4* vgp = (const uint4*)(Vg + (long)vrow * S_ + vcol);
  int klo = krow * KSTR + kcol;  // LDS elem offsets within a tile
  int vlo = vrow * VSTR + vcol;

  {  // preload tile 0 into buffer 0
    uint4 k0[4], v0[4];
#pragma unroll
    for (int u = 0; u < 4; u++) { k0[u] = kgp[u]; v0[u] = vgp[u]; }
    uint4* kw = (uint4*)(Ks + klo);
    uint4* vw = (uint4*)(Vs + vlo);
#pragma unroll
    for (int u = 0; u < 4; u++) { kw[u] = k0[u]; vw[u] = v0[u]; }
  }
  __syncthreads();

  f32x4 Of[8] = {};                   // O^T: col l16 = qrow, rows = hd (n*16 + quad*4 + r)
  float m_run = NEGINF, l_run = 0.f;  // per-lane state for qrow (wave*16 + l16)

  for (int kt = 0; kt <= qt; ++kt) {
    const bf16* kc = Ks + (kt & 1) * KTILE;
    const bf16* vc = Vs + (kt & 1) * VTILE;
    bool more = kt < qt;
    uint4 kr[4], vr[4];
    if (more) {  // issue next-tile loads now; latency overlaps compute below
      kgp += 1024; vgp += 8;
#pragma unroll
      for (int u = 0; u < 4; u++) { kr[u] = kgp[u]; vr[u] = vgp[u]; }
    }

    // S^T = K Q^T: A = K-frag (m = key), B = Q-frag (n = qrow)
    bool diag = (kt == qt);
    f32x4 sf[4];
#pragma unroll
    for (int jb = 0; jb < 4; jb++) {
      if (diag && jb > wave) {  // fully-masked key block on diagonal tile
        sf[jb] = (f32x4){NEGINF, NEGINF, NEGINF, NEGINF};
      } else {
        f32x4 a = {};
        const bf16* kbase = kc + (jb * 16 + l16) * KSTR + quad * 8;
#pragma unroll
        for (int kk = 0; kk < 4; kk++) {
          bf16x8 kf = *(const bf16x8*)(kbase + kk * 32);
          a = __builtin_amdgcn_mfma_f32_16x16x32_bf16(kf, qb[kk], a, 0, 0, 0);
        }
        sf[jb] = a;
      }
    }
    if (diag) {  // partial mask, jb == wave (unrolled -> constant indices only)
#pragma unroll
      for (int jb = 0; jb < 4; jb++)
        if (jb == wave) {
#pragma unroll
          for (int r = 0; r < 4; r++)
            if (quad * 4 + r > l16) sf[jb][r] = NEGINF;
        }
    }

    // per-lane row max over 16 vals + 2 cross-quad shuffles
    float mx = NEGINF;
#pragma unroll
    for (int jb = 0; jb < 4; jb++)
#pragma unroll
      for (int r = 0; r < 4; r++) mx = fmaxf(mx, sf[jb][r]);
    mx = fmaxf(mx, __shfl_xor(mx, 16));
    mx = fmaxf(mx, __shfl_xor(mx, 32));
    float mnew = fmaxf(m_run, mx);
    float alpha = __expf(m_run - mnew);
    m_run = mnew;

    // p = exp(s - m): stays in registers as the PV B-operand (s16x4 of bf16 bits)
    float ls = 0.f;
    s16x4 pk[4];
#pragma unroll
    for (int jb = 0; jb < 4; jb++) {
      float p0 = __expf(sf[jb][0] - mnew);
      float p1 = __expf(sf[jb][1] - mnew);
      float p2 = __expf(sf[jb][2] - mnew);
      float p3 = __expf(sf[jb][3] - mnew);
      ls += (p0 + p1) + (p2 + p3);
      s16x4 t;
      t.x = (short)bfb(p0); t.y = (short)bfb(p1);
      t.z = (short)bfb(p2); t.w = (short)bfb(p3);
      pk[jb] = t;
    }
    l_run = l_run * alpha + ls;
#pragma unroll
    for (int n = 0; n < 8; n++) Of[n] *= alpha;  // per-lane alpha: no shuffle

    // O^T += V^T P^T via 16x16x16 MFMA (A = V^T frag, B = pk from regs)
#pragma unroll
    for (int jb = 0; jb < 4; jb++) {
      if (diag && jb > wave) continue;  // p == 0
#pragma unroll
      for (int n = 0; n < 8; n++) {
        s16x4 va = *(const s16x4*)(vc + (n * 16 + l16) * VSTR + jb * 16 + quad * 4);
        Of[n] = __builtin_amdgcn_mfma_f32_16x16x16bf16_1k(va, pk[jb], Of[n], 0, 0, 0);
      }
    }

    if (more) {  // write prefetched tile into the idle buffer
      uint4* kw = (uint4*)(Ks + ((kt & 1) ^ 1) * KTILE + klo);
      uint4* vw = (uint4*)(Vs + ((kt & 1) ^ 1) * VTILE + vlo);
#pragma unroll
      for (int u = 0; u < 4; u++) { kw[u] = kr[u]; vw[u] = vr[u]; }
    }
    __syncthreads();
  }

  // epilogue: reduce l across quads (per-lane partials for qrow l16), packed 8B stores
  l_run += __shfl_xor(l_run, 16);
  l_run += __shfl_xor(l_run, 32);
  float inv = 1.0f / fmaxf(l_run, 1e-30f);
  bf16* Ob = O + ((long)(b * S_) + q0 + wave * 16 + l16) * D_ + h * HD_;
#pragma unroll
  for (int n = 0; n < 8; n++) {
    ushort4 w;
    w.x = bfb(Of[n][0] * inv); w.y = bfb(Of[n][1] * inv);
    w.z = bfb(Of[n][2] * inv); w.w = bfb(Of[n][3] * inv);
    *(ushort4*)(Ob + n * 16 + quad * 4) = w;
  }
}

// ---------------- launch ----------------
extern "C" void kernel_launch(void* const* d_in, const int* in_sizes, int n_in,
                              void* d_out, int out_size, void* d_ws, size_t ws_size,
                              hipStream_t stream) {
  const void* x  = d_in[0];
  const void* Wq = d_in[1];
  const void* Wk = d_in[2];
  const void* Wv = d_in[3];
  const void* Wo = d_in[4];
  bf16* ws = (bf16*)d_ws;
  int* flag = (int*)d_ws;

  // workspace (bf16 elem offsets), peak 23,068,688 elems = 46.1 MB (proven in r4)
  bf16* qkv   = ws + 16;        // 4096 x 2560          gemm1 -> rope
  bf16* Vtb   = ws + 10485776;  // 2 x 512 x 2048       gemm1 epilogue -> attn
  bf16* Qb    = ws + 12582928;  // 2x16x2048x128        rope -> attn
  bf16* wqkvT = ws + 12582928;  // 3072x2048 (overlaps Qb; dead before rope writes)
  bf16* Kb    = ws + 20971536;  // 2x4x2048x128         rope -> attn
  bf16* attno = ws + 16;        // reuse qkv            attn -> gemm2
  bf16* woT   = ws + 10485776;  // reuse Vtb/Qb region  (transposed after attn)

  dim3 tb(32, 8);
  detect_dtype<<<1, 256, 0, stream>>>((const unsigned*)x, flag);
  transpose_qkvw<<<dim3(64, 64, 3), tb, 0, stream>>>(Wq, Wk, Wv, wqkvT, flag);
  // qkv = x @ [Wq|Wk|Wv]; q,k cols -> qkv (ldc 2560), v cols -> Vtb transposed
  gemm_bt<<<dim3(QKVW / BN, (B_ * S_) / BM), 256, 0, stream>>>(
      x, wqkvT, qkv, B_ * S_, QKVW, D_, QKW, QKW, Vtb, QKW, flag, 1, 0);
  rope_scatter<<<B_ * S_, 256, 0, stream>>>(qkv, Qb, Kb);
  attn_kernel<<<dim3(S_ / 64, H_, B_), 256, 0, stream>>>(Qb, Kb, Vtb, attno);
  transpose_cvt<<<dim3(64, 64, 1), tb, 0, stream>>>(Wo, woT, 2048, 2048, flag);
  // out = attno @ Wo (output dtype per flag)
  gemm_bt<<<dim3(D_ / BN, (B_ * S_) / BM), 256, 0, stream>>>(
      attno, woT, d_out, B_ * S_, D_, D_, D_, D_, nullptr, 0, flag, 0, 1);
}

// Round 6
// 451.997 us; speedup vs baseline: 1.4503x; 1.3602x over previous
//
#include <hip/hip_runtime.h>

typedef __bf16 bf16;
typedef __bf16 bf16x8 __attribute__((ext_vector_type(8)));
typedef float f32x4 __attribute__((ext_vector_type(4)));
typedef short s16x4 __attribute__((ext_vector_type(4)));

#define B_ 2
#define S_ 2048
#define D_ 2048
#define H_ 16
#define HKV_ 4
#define HD_ 128
#define QKVW 3072
#define QKW 2560                    // q+k columns (V handled separately)
#define SCALE 0.08838834764831845f  // 1/sqrt(128)
#define NEGINF -30000.0f            // finite -inf: exp underflows to 0, no inf-inf

// async global->LDS DMA, 16B per lane; LDS dest = wave-uniform base + lane*16
__device__ inline void gload16(const void* g, void* l) {
  __builtin_amdgcn_global_load_lds((const __attribute__((address_space(1))) unsigned int*)g,
                                   (__attribute__((address_space(3))) unsigned int*)l, 16, 0, 0);
}

__device__ inline unsigned short bfb(float v) {
  union { bf16 h; unsigned short u; } c;
  c.h = (bf16)v;
  return c.u;
}

// ---------------- dtype detection: bf16 or fp32 inputs? ----------------
__global__ void detect_dtype(const unsigned* __restrict__ xw, int* __restrict__ flag) {
  __shared__ int cnt;
  if (threadIdx.x == 0) cnt = 0;
  __syncthreads();
  unsigned w = xw[(size_t)threadIdx.x * 16384];
  unsigned low = w & 0xFFFFu;
  int e = (int)((low >> 7) & 0xFF);
  int vote = (low == 0u || (e >= 100 && e <= 140)) ? 1 : 0;
  atomicAdd(&cnt, vote);
  __syncthreads();
  if (threadIdx.x == 0) *flag = (cnt >= 128) ? 1 : 0;  // 1 = bf16, 0 = fp32
}

// ---------------- fused Wq/Wk/Wv transpose -> wqkvT (B^T layout) ----------------
__global__ __launch_bounds__(256) void transpose_qkvw(
    const void* __restrict__ Wq, const void* __restrict__ Wk, const void* __restrict__ Wv,
    bf16* __restrict__ wqkvT, const int* __restrict__ flag) {
  int z = blockIdx.z;
  const void* in = (z == 0) ? Wq : (z == 1) ? Wk : Wv;
  int cols = (z == 0) ? 2048 : 512;
  bf16* out = wqkvT + ((z == 0) ? 0 : (z == 1) ? 2048 * 2048 : 2560 * 2048);
  if (blockIdx.x * 32 >= cols) return;
  int fm = *flag;
  __shared__ float tile[32][33];
  int c0 = blockIdx.x * 32, r0 = blockIdx.y * 32;
  int tx = threadIdx.x, ty = threadIdx.y;  // 32 x 8
#pragma unroll
  for (int i = 0; i < 32; i += 8) {
    long idx = (long)(r0 + ty + i) * cols + c0 + tx;
    tile[ty + i][tx] = fm ? (float)((const bf16*)in)[idx] : ((const float*)in)[idx];
  }
  __syncthreads();
#pragma unroll
  for (int i = 0; i < 32; i += 8)
    out[(long)(c0 + ty + i) * 2048 + r0 + tx] = (bf16)tile[tx][ty + i];
}

// ---------------- generic transpose (+dtype-adaptive read) for Wo ----------------
__global__ __launch_bounds__(256) void transpose_cvt(
    const void* __restrict__ in, bf16* __restrict__ out,
    long in_stride, long out_stride, const int* __restrict__ flag) {
  __shared__ float tile[32][33];
  int fm = *flag;
  int c0 = blockIdx.x * 32, r0 = blockIdx.y * 32;
  int tx = threadIdx.x, ty = threadIdx.y;
#pragma unroll
  for (int i = 0; i < 32; i += 8) {
    long idx = (long)(r0 + ty + i) * in_stride + c0 + tx;
    tile[ty + i][tx] = fm ? (float)((const bf16*)in)[idx] : ((const float*)in)[idx];
  }
  __syncthreads();
#pragma unroll
  for (int i = 0; i < 32; i += 8)
    out[(long)(c0 + ty + i) * out_stride + r0 + tx] = (bf16)tile[tx][ty + i];
}

// ---------------- GEMM: C = A * Bt^T (m97-style global_load_lds staging) ----------------
#define BM 128
#define BN 128
#define BK 32

__global__ __launch_bounds__(256) void gemm_bt(
    const void* __restrict__ A, const bf16* __restrict__ Bt, void* __restrict__ C,
    int M, int N, int K, int ldc, int ncmax,
    bf16* __restrict__ vt_out, int vcol0,
    const int* __restrict__ flag, int adyn, int cdyn) {
  alignas(16) __shared__ bf16 la[BM * BK];  // unpadded: DMA lane-linear layout
  alignas(16) __shared__ bf16 lb[BN * BK];
  int fm = flag ? *flag : 1;
  bool af32 = adyn && !fm;
  bool cf32 = cdyn && !fm;
  int tid = threadIdx.x;
  int wave = tid >> 6, lane = tid & 63;
  int wr = wave >> 1, wc = wave & 1;
  int quad = lane >> 4, l16 = lane & 15;
  int m0 = blockIdx.y * BM, n0 = blockIdx.x * BN;

  f32x4 acc[4][4] = {};

  // DMA coords: lane covers row (wave*16 + lane/4), 8-elem chunk (lane%4)
  int sr = (wave << 4) + (lane >> 2);
  int sc = (lane & 3) << 3;
  const bf16* gb0 = Bt + (long)(n0 + sr) * K + sc;
  const bf16* gb1 = Bt + (long)(n0 + 64 + sr) * K + sc;
  bf16* lb0 = lb + (wave << 9);
  bf16* lb1 = lb + 2048 + (wave << 9);
  bf16* la0 = la + (wave << 9);
  bf16* la1 = la + 2048 + (wave << 9);
  const bf16* ga0 = nullptr; const bf16* ga1 = nullptr;
  const float* gaf = nullptr;
  int fr = tid >> 1, fh = (tid & 1) << 4;  // fp32-A path: row, 16-elem half
  if (af32) gaf = (const float*)A + (long)(m0 + fr) * K + fh;
  else { ga0 = (const bf16*)A + (long)(m0 + sr) * K + sc;
         ga1 = (const bf16*)A + (long)(m0 + 64 + sr) * K + sc; }
  bf16* law = la + fr * BK + fh;

  for (int k0 = 0; k0 < K; k0 += BK) {
    __syncthreads();  // all readers of previous tile done
    gload16(gb0 + k0, lb0);
    gload16(gb1 + k0, lb1);
    if (af32) {
      const float* fp = gaf + k0;
      alignas(16) bf16 t[16];
#pragma unroll
      for (int u = 0; u < 16; u += 4) {
        float4 f = *(const float4*)(fp + u);
        t[u] = (bf16)f.x; t[u + 1] = (bf16)f.y; t[u + 2] = (bf16)f.z; t[u + 3] = (bf16)f.w;
      }
      *(uint4*)law = *(uint4*)t;
      *(uint4*)(law + 8) = *(uint4*)(t + 8);
    } else {
      gload16(ga0 + k0, la0);
      gload16(ga1 + k0, la1);
    }
    __syncthreads();  // vmcnt+lgkm drained by compiler before barrier -> tile visible

    const bf16* pa = la + ((wr << 6) + l16) * BK + (quad << 3);
    const bf16* pb = lb + ((wc << 6) + l16) * BK + (quad << 3);
    bf16x8 af[4], bfr[4];
#pragma unroll
    for (int i = 0; i < 4; i++) af[i] = *(const bf16x8*)(pa + (i << 4) * BK);
#pragma unroll
    for (int j = 0; j < 4; j++) bfr[j] = *(const bf16x8*)(pb + (j << 4) * BK);
#pragma unroll
    for (int i = 0; i < 4; i++)
#pragma unroll
      for (int j = 0; j < 4; j++)
        acc[i][j] = __builtin_amdgcn_mfma_f32_16x16x32_bf16(af[i], bfr[j], acc[i][j], 0, 0, 0);
  }

  // C/D layout: col = lane&15, row = quad*4 + reg
  if (vt_out && n0 >= vcol0) {
    // V region of gemm1: write V^T[b][hd][s] directly (packed 8B stores)
#pragma unroll
    for (int i = 0; i < 4; i++)
#pragma unroll
      for (int j = 0; j < 4; j++) {
        int col = n0 + (wc << 6) + (j << 4) + l16;
        int hdg = col - vcol0;                            // 0..511 = kh*128+hd
        int row0 = m0 + (wr << 6) + (i << 4) + (quad << 2);
        int bb = row0 >> 11, s = row0 & 2047;             // row0 % 4 == 0: no b crossing
        ushort4 p;
        p.x = bfb(acc[i][j][0]); p.y = bfb(acc[i][j][1]);
        p.z = bfb(acc[i][j][2]); p.w = bfb(acc[i][j][3]);
        *(ushort4*)(vt_out + (((long)(bb * 512 + hdg)) << 11) + s) = p;
      }
  } else {
#pragma unroll
    for (int i = 0; i < 4; i++)
#pragma unroll
      for (int j = 0; j < 4; j++) {
        int col = n0 + (wc << 6) + (j << 4) + l16;
        if (col >= ncmax) continue;
#pragma unroll
        for (int r = 0; r < 4; r++) {
          long row = m0 + (wr << 6) + (i << 4) + (quad << 2) + r;
          float v = acc[i][j][r];
          if (cf32) ((float*)C)[row * ldc + col] = v;
          else      ((bf16*)C)[row * ldc + col] = (bf16)v;
        }
      }
  }
}

// ---------------- RoPE + scatter (Q pre-scaled by 1/sqrt(d)) ----------------
__global__ __launch_bounds__(256) void rope_scatter(
    const bf16* __restrict__ qkv, bf16* __restrict__ Q, bf16* __restrict__ Ko) {
  int row = blockIdx.x;  // b*S + s
  int b = row >> 11, s = row & 2047;
  int tid = threadIdx.x;
  const bf16* src = qkv + (long)row * QKW;
#pragma unroll
  for (int it = 0; it < 4; ++it) {
    int p = tid + it * 256;
    int h = p >> 6, i = p & 63;
    float x1 = (float)src[h * 128 + 2 * i];
    float x2 = (float)src[h * 128 + 2 * i + 1];
    float theta = __expf(-0.14391156831212787f * (float)i);  // 10000^(-2i/128)
    float sn, cs;
    sincosf((float)s * theta, &sn, &cs);
    long qb = ((long)(b * H_ + h) * S_ + s) * HD_;
    Q[qb + i]      = (bf16)((x1 * cs - x2 * sn) * SCALE);
    Q[qb + 64 + i] = (bf16)((x1 * sn + x2 * cs) * SCALE);
  }
  {
    int kh = tid >> 6, i = tid & 63;
    float x1 = (float)src[2048 + kh * 128 + 2 * i];
    float x2 = (float)src[2048 + kh * 128 + 2 * i + 1];
    float theta = __expf(-0.14391156831212787f * (float)i);
    float sn, cs;
    sincosf((float)s * theta, &sn, &cs);
    long kb = ((long)(b * HKV_ + kh) * S_ + s) * HD_;
    Ko[kb + i]      = (bf16)(x1 * cs - x2 * sn);
    Ko[kb + 64 + i] = (bf16)(x1 * sn + x2 * cs);
  }
}

// ---------------- flash attention ----------------
// S^T = K Q^T (lane l16 = qrow, regs = 4 keys) -> per-lane softmax -> PV straight from
// registers (S-accum == B-operand layout of v_mfma_f32_16x16x16bf16_1k). K/V staged by
// global_load_lds DMA (zero data VGPRs, no spill risk), double-buffered, with XOR-swizzled
// per-lane SOURCE addressing so the lane-linear LDS image has conflict-free fragment reads.
#define KTILE 8192  // 64 rows x 128 elems
#define VTILE 8192  // 128 rows x 64 elems

__global__ __launch_bounds__(256) void attn_kernel(
    const bf16* __restrict__ Q, const bf16* __restrict__ K,
    const bf16* __restrict__ Vt, bf16* __restrict__ O) {
  alignas(16) __shared__ bf16 Ks[2 * KTILE];  // 32 KB
  alignas(16) __shared__ bf16 Vs[2 * VTILE];  // 32 KB
  int qt = (int)gridDim.x - 1 - (int)blockIdx.x;  // longest blocks dispatch first
  int h = blockIdx.y, b = blockIdx.z;
  int kh = h >> 2;
  int tid = threadIdx.x, wave = tid >> 6, lane = tid & 63;
  int quad = lane >> 4, l16 = lane & 15;
  int q0 = qt * 64;
  const bf16* Qg = Q + ((long)(b * H_ + h) * S_ + q0) * HD_;
  const bf16* Kg = K + ((long)(b * HKV_ + kh) * S_) * HD_;
  const bf16* Vg = Vt + ((long)(b * HKV_ + kh) * HD_) * S_;

  // Q B-fragments in registers (pre-scaled by 1/sqrt(d)); lane l16 = qrow
  bf16x8 qb[4];
  {
    const bf16* qrow = Qg + (wave * 16 + l16) * HD_ + quad * 8;
#pragma unroll
    for (int kk = 0; kk < 4; kk++) qb[kk] = *(const bf16x8*)(qrow + kk * 32);
  }

  // DMA source/dest offsets (elems). 16 calls/tile, call i = u*4+wave covers flat chunks
  // [i*64, i*64+64), chunk f: lane = f&63. K: r=f>>4, c=(f&15)^(r&15). V: v=f>>3, cv=(f&7)^(v&7).
  int kgo[4], vgo[4], klo[4], vlo[4];
#pragma unroll
  for (int u = 0; u < 4; u++) {
    int i = u * 4 + wave;
    int r = i * 4 + quad;                 // K row this lane fetches
    int c = l16 ^ (r & 15);               // swizzled chunk-in-row
    kgo[u] = r * HD_ + c * 8;
    klo[u] = i * 512;                     // wave-uniform LDS base (elems)
    int v = i * 8 + (lane >> 3);          // V^T row
    int cv = (lane & 7) ^ (v & 7);
    vgo[u] = v * S_ + cv * 8;
    vlo[u] = i * 512;
  }

  // preload tile 0 into buffer 0
#pragma unroll
  for (int u = 0; u < 4; u++) {
    gload16(Kg + kgo[u], Ks + klo[u]);
    gload16(Vg + vgo[u], Vs + vlo[u]);
  }

  f32x4 Of[8] = {};                   // O^T: col l16 = qrow, rows = hd
  float m_run = NEGINF, l_run = 0.f;  // per-lane state for qrow (wave*16 + l16)

  for (int kt = 0; kt <= qt; ++kt) {
    __syncthreads();  // drains DMA for buf (kt&1); prior readers of buf (kt&1)^1 done
    int p = kt & 1;
    if (kt < qt) {  // issue next-tile DMA into idle buffer; completes by next barrier
      const bf16* kn = Kg + (long)(kt + 1) * 8192;
      const bf16* vn = Vg + (long)(kt + 1) * 64;
      bf16* kd = Ks + (p ^ 1) * KTILE;
      bf16* vd = Vs + (p ^ 1) * VTILE;
#pragma unroll
      for (int u = 0; u < 4; u++) {
        gload16(kn + kgo[u], kd + klo[u]);
        gload16(vn + vgo[u], vd + vlo[u]);
      }
    }
    const bf16* kc = Ks + p * KTILE;
    const bf16* vc = Vs + p * VTILE;

    // S^T = K Q^T: A = K-frag (m = key), B = Q-frag (n = qrow)
    bool diag = (kt == qt);
    f32x4 sf[4];
#pragma unroll
    for (int jb = 0; jb < 4; jb++) {
      if (diag && jb > wave) {  // fully-masked key block on diagonal tile
        sf[jb] = (f32x4){NEGINF, NEGINF, NEGINF, NEGINF};
      } else {
        f32x4 a = {};
        const bf16* kbase = kc + (jb * 16 + l16) * 128;
#pragma unroll
        for (int kk = 0; kk < 4; kk++) {
          bf16x8 kf = *(const bf16x8*)(kbase + (((kk * 4 + quad) ^ l16) * 8));
          a = __builtin_amdgcn_mfma_f32_16x16x32_bf16(kf, qb[kk], a, 0, 0, 0);
        }
        sf[jb] = a;
      }
    }
    if (diag) {  // partial mask on key block jb == wave (constant indices only)
#pragma unroll
      for (int jb = 0; jb < 4; jb++)
        if (jb == wave) {
#pragma unroll
          for (int r = 0; r < 4; r++)
            if (quad * 4 + r > l16) sf[jb][r] = NEGINF;
        }
    }

    // per-lane row max + 2 cross-quad shuffles
    float mx = NEGINF;
#pragma unroll
    for (int jb = 0; jb < 4; jb++)
#pragma unroll
      for (int r = 0; r < 4; r++) mx = fmaxf(mx, sf[jb][r]);
    mx = fmaxf(mx, __shfl_xor(mx, 16));
    mx = fmaxf(mx, __shfl_xor(mx, 32));
    float mnew = fmaxf(m_run, mx);
    float alpha = __expf(m_run - mnew);
    m_run = mnew;

    // p = exp(s - m): stays in registers as the PV B-operand
    float ls = 0.f;
    s16x4 pk[4];
#pragma unroll
    for (int jb = 0; jb < 4; jb++) {
      float p0 = __expf(sf[jb][0] - mnew);
      float p1 = __expf(sf[jb][1] - mnew);
      float p2 = __expf(sf[jb][2] - mnew);
      float p3 = __expf(sf[jb][3] - mnew);
      ls += (p0 + p1) + (p2 + p3);
      s16x4 t;
      t.x = (short)bfb(p0); t.y = (short)bfb(p1);
      t.z = (short)bfb(p2); t.w = (short)bfb(p3);
      pk[jb] = t;
    }
    l_run = l_run * alpha + ls;
#pragma unroll
    for (int n = 0; n < 8; n++) Of[n] *= alpha;  // per-lane alpha: no shuffle

    // O^T += V^T P^T via 16x16x16 MFMA (A = V^T frag from swizzled LDS, B = pk regs)
#pragma unroll
    for (int jb = 0; jb < 4; jb++) {
      if (diag && jb > wave) continue;  // p == 0
      int swz = ((jb * 2 + (quad >> 1)) ^ 7) & 7;  // placeholder to keep pattern clear
#pragma unroll
      for (int n = 0; n < 8; n++) {
        int v = n * 16 + l16;
        const bf16* va_p = vc + v * 64 + (((jb * 2 + (quad >> 1)) ^ (l16 & 7)) * 8) + (quad & 1) * 4;
        s16x4 va = *(const s16x4*)va_p;
        Of[n] = __builtin_amdgcn_mfma_f32_16x16x16bf16_1k(va, pk[jb], Of[n], 0, 0, 0);
      }
      (void)swz;
    }
  }

  // epilogue: reduce l across quads, packed 8B stores
  l_run += __shfl_xor(l_run, 16);
  l_run += __shfl_xor(l_run, 32);
  float inv = 1.0f / fmaxf(l_run, 1e-30f);
  bf16* Ob = O + ((long)(b * S_) + q0 + wave * 16 + l16) * D_ + h * HD_;
#pragma unroll
  for (int n = 0; n < 8; n++) {
    ushort4 w;
    w.x = bfb(Of[n][0] * inv); w.y = bfb(Of[n][1] * inv);
    w.z = bfb(Of[n][2] * inv); w.w = bfb(Of[n][3] * inv);
    *(ushort4*)(Ob + n * 16 + quad * 4) = w;
  }
}

// ---------------- launch ----------------
extern "C" void kernel_launch(void* const* d_in, const int* in_sizes, int n_in,
                              void* d_out, int out_size, void* d_ws, size_t ws_size,
                              hipStream_t stream) {
  const void* x  = d_in[0];
  const void* Wq = d_in[1];
  const void* Wk = d_in[2];
  const void* Wv = d_in[3];
  const void* Wo = d_in[4];
  bf16* ws = (bf16*)d_ws;
  int* flag = (int*)d_ws;

  // workspace (bf16 elem offsets), peak 23,068,688 elems = 46.1 MB (proven)
  bf16* qkv   = ws + 16;        // 4096 x 2560          gemm1 -> rope
  bf16* Vtb   = ws + 10485776;  // 2 x 512 x 2048       gemm1 epilogue -> attn
  bf16* Qb    = ws + 12582928;  // 2x16x2048x128        rope -> attn
  bf16* wqkvT = ws + 12582928;  // 3072x2048 (overlaps Qb; dead before rope writes)
  bf16* Kb    = ws + 20971536;  // 2x4x2048x128         rope -> attn
  bf16* attno = ws + 16;        // reuse qkv            attn -> gemm2
  bf16* woT   = ws + 10485776;  // reuse Vtb/Qb region  (transposed after attn)

  dim3 tb(32, 8);
  detect_dtype<<<1, 256, 0, stream>>>((const unsigned*)x, flag);
  transpose_qkvw<<<dim3(64, 64, 3), tb, 0, stream>>>(Wq, Wk, Wv, wqkvT, flag);
  // qkv = x @ [Wq|Wk|Wv]; q,k cols -> qkv (ldc 2560), v cols -> Vtb transposed
  gemm_bt<<<dim3(QKVW / BN, (B_ * S_) / BM), 256, 0, stream>>>(
      x, wqkvT, qkv, B_ * S_, QKVW, D_, QKW, QKW, Vtb, QKW, flag, 1, 0);
  rope_scatter<<<B_ * S_, 256, 0, stream>>>(qkv, Qb, Kb);
  attn_kernel<<<dim3(S_ / 64, H_, B_), 256, 0, stream>>>(Qb, Kb, Vtb, attno);
  transpose_cvt<<<dim3(64, 64, 1), tb, 0, stream>>>(Wo, woT, 2048, 2048, flag);
  // out = attno @ Wo (output dtype per flag)
  gemm_bt<<<dim3(D_ / BN, (B_ * S_) / BM), 256, 0, stream>>>(
      attno, woT, d_out, B_ * S_, D_, D_, D_, D_, nullptr, 0, flag, 0, 1);
}